// Round 1
// baseline (411.464 us; speedup 1.0000x reference)
//
#include <hip/hip_runtime.h>
#include <hip/hip_bf16.h>

typedef __attribute__((ext_vector_type(8))) short short8;
typedef __attribute__((ext_vector_type(4))) float f32x4;
typedef __attribute__((ext_vector_type(2))) float f32x2;
typedef __attribute__((ext_vector_type(2))) unsigned int uint2v;
typedef __attribute__((ext_vector_type(4))) unsigned int u32x4;

#define LOG2E 1.4426950408889634f
#define LN2   0.6931471805599453f

__device__ __forceinline__ unsigned short f2bf(float f) {
    union { float f; unsigned u; } v; v.f = f;
    unsigned u = v.u;
    u += 0x7fffu + ((u >> 16) & 1u);   // RNE, finite
    return (unsigned short)(u >> 16);
}
__device__ __forceinline__ float bf2f(unsigned short h) {
    union { unsigned u; float f; } v; v.u = ((unsigned)h) << 16;
    return v.f;
}
__device__ __forceinline__ float bitf(unsigned u) {
    union { unsigned u; float f; } v; v.u = u;
    return v.f;
}
__device__ __forceinline__ unsigned pk_bf16(float a, float b) {
    __hip_bfloat162 t = __float22bfloat162_rn(float2{a, b});   // v_cvt_pk_bf16_f32
    union { __hip_bfloat162 b; unsigned u; } v; v.b = t;
    return v.u;
}
// packed FP32 FMA (CDNA2+ VOP3P): d = a*b + c elementwise on a float2 pair
__device__ __forceinline__ f32x2 pk_fma2(f32x2 a, f32x2 b, f32x2 c) {
    f32x2 d;
    asm("v_pk_fma_f32 %0, %1, %2, %3" : "=v"(d) : "v"(a), "v"(b), "v"(c));
    return d;
}

// ---------------------------------------------------------------------------
// Wave tile = 64 rows x 64 cols. Wave w owns phys cols [w*64, w*64+64).
// Tile->column map: col tile ct (0..3), frag col i: phys n = w*64 + 4*i + ct
// (4 adjacent phys cols per lane -> b64 activation writes).
// Pack order per layer: frag-set index ((w*NKS + ks)*4 + ct) -> a wave's
// layer slice is one contiguous 32 KB stream.
//   wp[(((w*NKS+ks)*4+ct)*64 + lane)*8 + j] = W[k][n],
//   k = ks*32 + (lane>>4)*8 + j,  n = w*64 + 4*(lane&15) + ct.
// W0: hi/lo split rows [wh,wl,wh] per input dim (K=9 pad 32, NKS=1).
// Gaussian folded: g = exp2(np*(x+b)^2) = exp2((np*x + c1)*x + c2),
//   np = -log2(e)/(2 sigma^2), c1 = 2 np b, c2 = np b^2.
// negc layout per layer l (768 floats): [np(256) | c1(256) | c2(256)].
// ---------------------------------------------------------------------------
__global__ void pack_kernel(const float* __restrict__ W0, const float* __restrict__ W1,
                            const float* __restrict__ W2,
                            const float* __restrict__ s0, const float* __restrict__ s1,
                            const float* __restrict__ s2,
                            const float* __restrict__ b0, const float* __restrict__ b1,
                            const float* __restrict__ b2,
                            unsigned short* __restrict__ wp, float* __restrict__ negc) {
    int tid = blockIdx.x * 256 + threadIdx.x;    // 0 .. 139263
    if (tid < 8192) {                            // W0 (NKS=1)
        int j = tid & 7, lane = (tid >> 3) & 63, ct = (tid >> 9) & 3, w = tid >> 11;
        int k = ((lane >> 4) * 8) + j;           // 0..31
        int n = w * 64 + 4 * (lane & 15) + ct;
        unsigned short v = 0;
        if (k < 9) {
            int d = k / 3, m = k - d * 3;        // m: 0->wh 1->wl 2->wh
            float wv = W0[d * 256 + n];
            unsigned short wh = f2bf(wv);
            v = (m == 1) ? f2bf(wv - bf2f(wh)) : wh;
        }
        wp[tid] = v;
    } else if (tid < 139264) {                   // W1 / W2 (NKS=8)
        int e = tid - 8192;
        const float* W = W1;
        if (e >= 65536) { W = W2; e -= 65536; }
        int j = e & 7, lane = (e >> 3) & 63, ct = (e >> 9) & 3, ks = (e >> 11) & 7, w = e >> 14;
        int k = ks * 32 + ((lane >> 4) * 8) + j;
        int n = w * 64 + 4 * (lane & 15) + ct;
        wp[tid] = f2bf(W[k * 256 + n]);
    }
    if (tid < 768) {
        int l = tid >> 8, n = tid & 255;
        const float* s = (l == 0) ? s0 : (l == 1 ? s1 : s2);
        const float* b = (l == 0) ? b0 : (l == 1 ? b1 : b2);
        float sv = s[n], bv = b[n];
        float np = -LOG2E / (2.0f * sv * sv);
        negc[l * 768 + n]       = np;
        negc[l * 768 + 256 + n] = 2.0f * np * bv;
        negc[l * 768 + 512 + n] = np * bv * bv;
    }
}

constexpr int ROWS = 64;     // rows per block (256 threads = 4 waves)
constexpr int HSTR = 264;    // h row stride, bf16 elems (+8 pad; 528 B)
constexpr int ASTR = 40;     // A0 row stride (80 B)

// One MFMA layer. Each wave: all 64 rows x its 64 cols. Per ks: 4 A-frags
// (rg) + 4 W-frags (ct, contiguous stream) -> 16 MFMAs (each load feeds 4).
// acc[rg][ct]; activations packed to regs BEFORE the presync barrier.
// Activation: 2 packed-FMAs + exp2 per element (bias folded into c1/c2).
template <int NKS, int SSTR>
__device__ __forceinline__ void layer(const unsigned short* __restrict__ src,
                                      const unsigned short* __restrict__ wpk,
                                      const float* __restrict__ ncp,
                                      unsigned short* __restrict__ hdst,
                                      int w, int i16, int q, bool presync) {
    f32x4 acc[4][4];
#pragma unroll
    for (int rg = 0; rg < 4; ++rg)
#pragma unroll
        for (int ct = 0; ct < 4; ++ct)
            acc[rg][ct] = f32x4{0.f, 0.f, 0.f, 0.f};

    const int lane = q * 16 + i16;
    const short8* wp8 = (const short8*)wpk + (w * NKS * 4) * 64 + lane;
    const unsigned short* abase = src + i16 * SSTR + q * 8;

#pragma unroll
    for (int ks = 0; ks < NKS; ++ks) {
        short8 a[4];
#pragma unroll
        for (int rg = 0; rg < 4; ++rg)
            a[rg] = *(const short8*)(abase + rg * 16 * SSTR + ks * 32);
#pragma unroll
        for (int ct = 0; ct < 4; ++ct) {
            short8 wf = wp8[(ks * 4 + ct) * 64];
#pragma unroll
            for (int rg = 0; rg < 4; ++rg)
                acc[rg][ct] = __builtin_amdgcn_mfma_f32_16x16x32_bf16(a[rg], wf, acc[rg][ct], 0, 0, 0);
        }
    }

    // ---- activation math BEFORE barrier ----
    const int ce = w * 64 + 4 * i16;
    const f32x4 np = *(const f32x4*)(ncp + ce);
    const f32x4 C1 = *(const f32x4*)(ncp + 256 + ce);
    const f32x4 C2 = *(const f32x4*)(ncp + 512 + ce);
    f32x2 npb[4], c1b[4], c2b[4];
#pragma unroll
    for (int ct = 0; ct < 4; ++ct) {
        npb[ct] = f32x2{np[ct], np[ct]};
        c1b[ct] = f32x2{C1[ct], C1[ct]};
        c2b[ct] = f32x2{C2[ct], C2[ct]};
    }
    uint2v av[4][4];
#pragma unroll
    for (int rg = 0; rg < 4; ++rg) {
        float gg[4][4];   // [rr][ct]
#pragma unroll
        for (int ct = 0; ct < 4; ++ct) {
            f32x2 xlo = f32x2{acc[rg][ct][0], acc[rg][ct][1]};
            f32x2 xhi = f32x2{acc[rg][ct][2], acc[rg][ct][3]};
            f32x2 ulo = pk_fma2(npb[ct], xlo, c1b[ct]);
            f32x2 uhi = pk_fma2(npb[ct], xhi, c1b[ct]);
            f32x2 ylo = pk_fma2(ulo, xlo, c2b[ct]);
            f32x2 yhi = pk_fma2(uhi, xhi, c2b[ct]);
            gg[0][ct] = __builtin_amdgcn_exp2f(ylo[0]);
            gg[1][ct] = __builtin_amdgcn_exp2f(ylo[1]);
            gg[2][ct] = __builtin_amdgcn_exp2f(yhi[0]);
            gg[3][ct] = __builtin_amdgcn_exp2f(yhi[1]);
        }
#pragma unroll
        for (int rr = 0; rr < 4; ++rr) {
            uint2v v;
            v[0] = pk_bf16(gg[rr][0], gg[rr][1]);
            v[1] = pk_bf16(gg[rr][2], gg[rr][3]);
            av[rg][rr] = v;
        }
    }
    if (presync) __syncthreads();   // all reads of hdst done before overwrite
#pragma unroll
    for (int rg = 0; rg < 4; ++rg) {
        int rbase = rg * 16 + q * 4;
#pragma unroll
        for (int rr = 0; rr < 4; ++rr)
            *(uint2v*)&hdst[(rbase + rr) * HSTR + ce] = av[rg][rr];
    }
    __syncthreads();
}

__global__ __launch_bounds__(256, 3) void mlp_kernel(
    const float* __restrict__ pos,
    const float* __restrict__ W3, const float* __restrict__ b3,
    const unsigned short* __restrict__ Wp,
    const float* __restrict__ negc,
    float* __restrict__ out)
{
    __shared__ unsigned short h[ROWS * HSTR];   // 33792 B
    __shared__ unsigned short A0[ROWS * ASTR];  // 5120 B

    const int tid  = threadIdx.x;
    const int lane = tid & 63;
    const int wave = tid >> 6;                  // column group (0..3)
    const int i16  = lane & 15, q = lane >> 4;
    const long row0 = (long)blockIdx.x * ROWS;

    // ---- build A0: row r = [p0h,p0h,p0l, p1h,p1h,p1l, p2h,p2h,p2l, 0...] ----
    if (tid < ROWS) {
        const float* pp = pos + (row0 + tid) * 3;
        float p0 = pp[0], p1 = pp[1], p2 = pp[2];
        short h0 = (short)f2bf(p0); short l0 = (short)f2bf(p0 - bf2f((unsigned short)h0));
        short h1 = (short)f2bf(p1); short l1 = (short)f2bf(p1 - bf2f((unsigned short)h1));
        short h2 = (short)f2bf(p2); short l2 = (short)f2bf(p2 - bf2f((unsigned short)h2));
        unsigned short* arow = A0 + tid * ASTR;
        *(short8*)(arow + 0)  = short8{h0, h0, l0, h1, h1, l1, h2, h2};
        *(short8*)(arow + 8)  = short8{l2, 0, 0, 0, 0, 0, 0, 0};
        *(short8*)(arow + 16) = short8{0, 0, 0, 0, 0, 0, 0, 0};
        *(short8*)(arow + 24) = short8{0, 0, 0, 0, 0, 0, 0, 0};
    }
    __syncthreads();

    // ---- layer 0 (MFMA K=32 hi/lo), layers 1,2 ----
    layer<1, ASTR>(A0, Wp,         negc,        h, wave, i16, q, false);
    layer<8, HSTR>(h,  Wp + 8192,  negc + 768,  h, wave, i16, q, true);
    layer<8, HSTR>(h,  Wp + 73728, negc + 1536, h, wave, i16, q, true);

    // ---- layer 4: dot(h_row, W3) + softplus(beta=1, thr=8) ----
    {
        int r = tid >> 2, qq = tid & 3;
        const unsigned short* hrow = h + r * HSTR;
        f32x2 sa = {0.f, 0.f}, sb = {0.f, 0.f};
#pragma unroll
        for (int i = 0; i < 8; ++i) {
            int c = (qq + 4 * i) * 8;
            u32x4 hv = *(const u32x4*)(hrow + c);       // 8 bf16
            f32x4 wA = *(const f32x4*)(W3 + c);
            f32x4 wB = *(const f32x4*)(W3 + c + 4);
            f32x2 p0 = f32x2{bitf(hv[0] << 16), bitf(hv[0] & 0xffff0000u)};
            f32x2 p1 = f32x2{bitf(hv[1] << 16), bitf(hv[1] & 0xffff0000u)};
            f32x2 p2 = f32x2{bitf(hv[2] << 16), bitf(hv[2] & 0xffff0000u)};
            f32x2 p3 = f32x2{bitf(hv[3] << 16), bitf(hv[3] & 0xffff0000u)};
            sa = pk_fma2(p0, f32x2{wA[0], wA[1]}, sa);
            sb = pk_fma2(p1, f32x2{wA[2], wA[3]}, sb);
            sa = pk_fma2(p2, f32x2{wB[0], wB[1]}, sa);
            sb = pk_fma2(p3, f32x2{wB[2], wB[3]}, sb);
        }
        float s = sa[0] + sa[1] + sb[0] + sb[1];
        s += __shfl_xor(s, 1);
        s += __shfl_xor(s, 2);
        if (qq == 0) {
            float x  = s + b3[0];
            float xm = fminf(x, 8.0f);
            float e  = __builtin_amdgcn_exp2f(xm * LOG2E);
            float sp = __builtin_amdgcn_logf(1.0f + e) * LN2;
            out[row0 + r] = (x > 8.0f) ? x : sp;
        }
    }
}

extern "C" void kernel_launch(void* const* d_in, const int* in_sizes, int n_in,
                              void* d_out, int out_size, void* d_ws, size_t ws_size,
                              hipStream_t stream) {
    const float* pos = (const float*)d_in[0];
    const float* W0  = (const float*)d_in[1];
    const float* b0  = (const float*)d_in[2];
    const float* W1  = (const float*)d_in[3];
    const float* b1  = (const float*)d_in[4];
    const float* W2  = (const float*)d_in[5];
    const float* b2  = (const float*)d_in[6];
    const float* W3  = (const float*)d_in[7];
    const float* b3  = (const float*)d_in[8];
    const float* s0  = (const float*)d_in[9];
    const float* s1  = (const float*)d_in[10];
    const float* s2  = (const float*)d_in[11];

    unsigned short* wp = (unsigned short*)d_ws;              // 139264 bf16
    float* negc = (float*)((char*)d_ws + 278528);            // 2304 fp32: 3 x [np|c1|c2]

    pack_kernel<<<544, 256, 0, stream>>>(W0, W1, W2, s0, s1, s2, b0, b1, b2, wp, negc);

    int nrows = in_sizes[0] / 3;          // 1048576
    int nblk  = nrows / ROWS;             // 16384
    mlp_kernel<<<nblk, 256, 0, stream>>>(pos, W3, b3, wp, negc,
                                         (float*)d_out);
}

// Round 2
// 400.294 us; speedup vs baseline: 1.0279x; 1.0279x over previous
//
#include <hip/hip_runtime.h>
#include <hip/hip_bf16.h>

typedef __attribute__((ext_vector_type(8))) short short8;
typedef __attribute__((ext_vector_type(4))) float f32x4;
typedef __attribute__((ext_vector_type(2))) float f32x2;
typedef __attribute__((ext_vector_type(2))) unsigned int uint2v;

#define LOG2E 1.4426950408889634f
#define LN2   0.6931471805599453f

__device__ __forceinline__ unsigned short f2bf(float f) {
    union { float f; unsigned u; } v; v.f = f;
    unsigned u = v.u;
    u += 0x7fffu + ((u >> 16) & 1u);   // RNE, finite
    return (unsigned short)(u >> 16);
}
__device__ __forceinline__ float bf2f(unsigned short h) {
    union { unsigned u; float f; } v; v.u = ((unsigned)h) << 16;
    return v.f;
}
__device__ __forceinline__ unsigned pk_bf16(float a, float b) {
    __hip_bfloat162 t = __float22bfloat162_rn(float2{a, b});   // v_cvt_pk_bf16_f32
    union { __hip_bfloat162 b; unsigned u; } v; v.b = t;
    return v.u;
}
// packed FP32 FMA (VOP3P): d = a*b + c elementwise on a float2 pair
__device__ __forceinline__ f32x2 pk_fma2(f32x2 a, f32x2 b, f32x2 c) {
    f32x2 d;
    asm("v_pk_fma_f32 %0, %1, %2, %3" : "=v"(d) : "v"(a), "v"(b), "v"(c));
    return d;
}

// ---------------------------------------------------------------------------
// Wave tile = 64 rows x 64 cols. Wave w owns phys cols [w*64, w*64+64).
// Tile->column map: col tile ct (0..3), frag col i: phys n = w*64 + 4*i + ct
// (4 adjacent phys cols per lane -> b64 activation writes).
// Pack order per layer: frag-set index ((w*NKS + ks)*4 + ct) -> a wave's
// layer slice is one contiguous 32 KB stream.
//   wp[(((w*NKS+ks)*4+ct)*64 + lane)*8 + j] = W[k][n],
//   k = ks*32 + (lane>>4)*8 + j,  n = w*64 + 4*(lane&15) + ct.
// W0: hi/lo split rows [wh,wl,wh] per input dim (K=9 pad 32, NKS=1).
// W3: hi/lo split into 2 B-columns (n=0: wh, n=1: wl), per-wave K-slice 64
//   at wp+139264: wp[139264 + (((w*2+ks)*64+lane)*8 + j)],
//   k = w*64 + ks*32 + (lane>>4)*8 + j; zero for (lane&15) >= 2.
// Gaussian folded: g = exp2(np*(x+b)^2) = exp2((np*x + c1)*x + c2),
//   np = -log2(e)/(2 sigma^2), c1 = 2 np b, c2 = np b^2.
// negc layout per layer l (768 floats): [np(256) | c1(256) | c2(256)].
// ---------------------------------------------------------------------------
__global__ void pack_kernel(const float* __restrict__ W0, const float* __restrict__ W1,
                            const float* __restrict__ W2, const float* __restrict__ W3,
                            const float* __restrict__ s0, const float* __restrict__ s1,
                            const float* __restrict__ s2,
                            const float* __restrict__ b0, const float* __restrict__ b1,
                            const float* __restrict__ b2,
                            unsigned short* __restrict__ wp, float* __restrict__ negc) {
    int tid = blockIdx.x * 256 + threadIdx.x;    // 0 .. 143359
    if (tid < 8192) {                            // W0 (NKS=1)
        int j = tid & 7, lane = (tid >> 3) & 63, ct = (tid >> 9) & 3, w = tid >> 11;
        int k = ((lane >> 4) * 8) + j;           // 0..31
        int n = w * 64 + 4 * (lane & 15) + ct;
        unsigned short v = 0;
        if (k < 9) {
            int d = k / 3, m = k - d * 3;        // m: 0->wh 1->wl 2->wh
            float wv = W0[d * 256 + n];
            unsigned short wh = f2bf(wv);
            v = (m == 1) ? f2bf(wv - bf2f(wh)) : wh;
        }
        wp[tid] = v;
    } else if (tid < 139264) {                   // W1 / W2 (NKS=8)
        int e = tid - 8192;
        const float* W = W1;
        if (e >= 65536) { W = W2; e -= 65536; }
        int j = e & 7, lane = (e >> 3) & 63, ct = (e >> 9) & 3, ks = (e >> 11) & 7, w = e >> 14;
        int k = ks * 32 + ((lane >> 4) * 8) + j;
        int n = w * 64 + 4 * (lane & 15) + ct;
        wp[tid] = f2bf(W[k * 256 + n]);
    } else if (tid < 143360) {                   // W3 hi/lo (2 B-cols)
        int e = tid - 139264;
        int j = e & 7, lane = (e >> 3) & 63, ks = (e >> 9) & 1, w = e >> 10;
        int i16p = lane & 15, qp = lane >> 4;
        int k = w * 64 + ks * 32 + qp * 8 + j;
        float wv = W3[k];
        unsigned short wh = f2bf(wv);
        unsigned short v = 0;
        if (i16p == 0) v = wh;
        else if (i16p == 1) v = f2bf(wv - bf2f(wh));
        wp[139264 + e] = v;
    }
    if (tid < 768) {
        int l = tid >> 8, n = tid & 255;
        const float* s = (l == 0) ? s0 : (l == 1 ? s1 : s2);
        const float* b = (l == 0) ? b0 : (l == 1 ? b1 : b2);
        float sv = s[n], bv = b[n];
        float np = -LOG2E / (2.0f * sv * sv);
        negc[l * 768 + n]       = np;
        negc[l * 768 + 256 + n] = 2.0f * np * bv;
        negc[l * 768 + 512 + n] = np * bv * bv;
    }
}

constexpr int ROWS = 64;     // rows per block (256 threads = 4 waves)
constexpr int HSTR = 264;    // h row stride, bf16 elems (+8 pad; 528 B)
constexpr int ASTR = 40;     // A0 row stride (80 B)

// One MFMA layer. Each wave: all 64 rows x its 64 cols. Per ks: 4 A-frags
// (rg) + 4 W-frags (ct). Weight frags are DOUBLE-BUFFERED: group ks+1's 4
// global loads are issued before computing group ks, so the ~200cy L2
// latency hides under one ks-group of DS+MFMA work.
// acc[rg][ct]; activations packed to regs BEFORE the presync barrier.
// Activation: 2 packed-FMAs + exp2 per element (bias folded into c1/c2).
template <int NKS, int SSTR>
__device__ __forceinline__ void layer(const unsigned short* __restrict__ src,
                                      const unsigned short* __restrict__ wpk,
                                      const float* __restrict__ ncp,
                                      unsigned short* __restrict__ hdst,
                                      int w, int i16, int q, bool presync) {
    f32x4 acc[4][4];
#pragma unroll
    for (int rg = 0; rg < 4; ++rg)
#pragma unroll
        for (int ct = 0; ct < 4; ++ct)
            acc[rg][ct] = f32x4{0.f, 0.f, 0.f, 0.f};

    const int lane = q * 16 + i16;
    const short8* wp8 = (const short8*)wpk + (w * NKS * 4) * 64 + lane;
    const unsigned short* abase = src + i16 * SSTR + q * 8;

    short8 wbufA[4], wbufB[4];
#pragma unroll
    for (int ct = 0; ct < 4; ++ct) wbufA[ct] = wp8[ct * 64];

#pragma unroll
    for (int ks = 0; ks < NKS; ++ks) {
        // prefetch next ks-group into the other buffer (static ping-pong)
        if (ks + 1 < NKS) {
#pragma unroll
            for (int ct = 0; ct < 4; ++ct) {
                short8 t = wp8[((ks + 1) * 4 + ct) * 64];
                if (ks & 1) wbufA[ct] = t; else wbufB[ct] = t;
            }
        }
        short8 a[4];
#pragma unroll
        for (int rg = 0; rg < 4; ++rg)
            a[rg] = *(const short8*)(abase + rg * 16 * SSTR + ks * 32);
#pragma unroll
        for (int ct = 0; ct < 4; ++ct) {
            short8 wf = (ks & 1) ? wbufB[ct] : wbufA[ct];
#pragma unroll
            for (int rg = 0; rg < 4; ++rg)
                acc[rg][ct] = __builtin_amdgcn_mfma_f32_16x16x32_bf16(a[rg], wf, acc[rg][ct], 0, 0, 0);
        }
    }

    // ---- activation math BEFORE barrier ----
    const int ce = w * 64 + 4 * i16;
    const f32x4 np = *(const f32x4*)(ncp + ce);
    const f32x4 C1 = *(const f32x4*)(ncp + 256 + ce);
    const f32x4 C2 = *(const f32x4*)(ncp + 512 + ce);
    f32x2 npb[4], c1b[4], c2b[4];
#pragma unroll
    for (int ct = 0; ct < 4; ++ct) {
        npb[ct] = f32x2{np[ct], np[ct]};
        c1b[ct] = f32x2{C1[ct], C1[ct]};
        c2b[ct] = f32x2{C2[ct], C2[ct]};
    }
    uint2v av[4][4];
#pragma unroll
    for (int rg = 0; rg < 4; ++rg) {
        float gg[4][4];   // [rr][ct]
#pragma unroll
        for (int ct = 0; ct < 4; ++ct) {
            f32x2 xlo = f32x2{acc[rg][ct][0], acc[rg][ct][1]};
            f32x2 xhi = f32x2{acc[rg][ct][2], acc[rg][ct][3]};
            f32x2 ulo = pk_fma2(npb[ct], xlo, c1b[ct]);
            f32x2 uhi = pk_fma2(npb[ct], xhi, c1b[ct]);
            f32x2 ylo = pk_fma2(ulo, xlo, c2b[ct]);
            f32x2 yhi = pk_fma2(uhi, xhi, c2b[ct]);
            gg[0][ct] = __builtin_amdgcn_exp2f(ylo[0]);
            gg[1][ct] = __builtin_amdgcn_exp2f(ylo[1]);
            gg[2][ct] = __builtin_amdgcn_exp2f(yhi[0]);
            gg[3][ct] = __builtin_amdgcn_exp2f(yhi[1]);
        }
#pragma unroll
        for (int rr = 0; rr < 4; ++rr) {
            uint2v v;
            v[0] = pk_bf16(gg[rr][0], gg[rr][1]);
            v[1] = pk_bf16(gg[rr][2], gg[rr][3]);
            av[rg][rr] = v;
        }
    }
    if (presync) __syncthreads();   // all reads of hdst done before overwrite
#pragma unroll
    for (int rg = 0; rg < 4; ++rg) {
        int rbase = rg * 16 + q * 4;
#pragma unroll
        for (int rr = 0; rr < 4; ++rr)
            *(uint2v*)&hdst[(rbase + rr) * HSTR + ce] = av[rg][rr];
    }
    __syncthreads();
}

__global__ __launch_bounds__(256, 3) void mlp_kernel(
    const float* __restrict__ pos,
    const float* __restrict__ b3,
    const unsigned short* __restrict__ Wp,
    const float* __restrict__ negc,
    float* __restrict__ out)
{
    __shared__ unsigned short h[ROWS * HSTR];   // 33792 B
    __shared__ unsigned short A0[ROWS * ASTR];  // 5120 B (reused as f32 scratch)

    const int tid  = threadIdx.x;
    const int lane = tid & 63;
    const int wave = tid >> 6;                  // column group (0..3)
    const int i16  = lane & 15, q = lane >> 4;
    const long row0 = (long)blockIdx.x * ROWS;

    // ---- build A0: row r = [p0h,p0h,p0l, p1h,p1h,p1l, p2h,p2h,p2l, 0...] ----
    if (tid < ROWS) {
        const float* pp = pos + (row0 + tid) * 3;
        float p0 = pp[0], p1 = pp[1], p2 = pp[2];
        short h0 = (short)f2bf(p0); short l0 = (short)f2bf(p0 - bf2f((unsigned short)h0));
        short h1 = (short)f2bf(p1); short l1 = (short)f2bf(p1 - bf2f((unsigned short)h1));
        short h2 = (short)f2bf(p2); short l2 = (short)f2bf(p2 - bf2f((unsigned short)h2));
        unsigned short* arow = A0 + tid * ASTR;
        *(short8*)(arow + 0)  = short8{h0, h0, l0, h1, h1, l1, h2, h2};
        *(short8*)(arow + 8)  = short8{l2, 0, 0, 0, 0, 0, 0, 0};
        *(short8*)(arow + 16) = short8{0, 0, 0, 0, 0, 0, 0, 0};
        *(short8*)(arow + 24) = short8{0, 0, 0, 0, 0, 0, 0, 0};
    }
    __syncthreads();

    // ---- layer 0 (MFMA K=32 hi/lo), layers 1,2 ----
    layer<1, ASTR>(A0, Wp,         negc,        h, wave, i16, q, false);
    layer<8, HSTR>(h,  Wp + 8192,  negc + 768,  h, wave, i16, q, true);
    layer<8, HSTR>(h,  Wp + 73728, negc + 1536, h, wave, i16, q, true);

    // ---- layer 3: per-wave K-slice dot via MFMA (hi/lo W3 in B-cols 0,1) ----
    {
        const short8* w3p = (const short8*)(Wp + 139264) + (wave * 2) * 64 + lane;
        const unsigned short* ab3 = h + i16 * HSTR + wave * 64 + q * 8;
        f32x4 acc3[4];
#pragma unroll
        for (int rg = 0; rg < 4; ++rg) acc3[rg] = f32x4{0.f, 0.f, 0.f, 0.f};
#pragma unroll
        for (int ks = 0; ks < 2; ++ks) {
            short8 wf = w3p[ks * 64];
#pragma unroll
            for (int rg = 0; rg < 4; ++rg) {
                short8 a = *(const short8*)(ab3 + rg * 16 * HSTR + ks * 32);
                acc3[rg] = __builtin_amdgcn_mfma_f32_16x16x32_bf16(a, wf, acc3[rg], 0, 0, 0);
            }
        }
        // acc3[rg][rr]: col = i16 (0: wh-part, 1: wl-part), row = rg*16+q*4+rr
        float* scr = (float*)A0;   // [wave*2+i16][64 rows] = 2 KB
        if (i16 < 2) {
#pragma unroll
            for (int rg = 0; rg < 4; ++rg)
                *(f32x4*)&scr[(wave * 2 + i16) * 64 + rg * 16 + q * 4] = acc3[rg];
        }
        __syncthreads();
        if (tid < 64) {
            float s = 0.f;
#pragma unroll
            for (int g = 0; g < 8; ++g) s += scr[g * 64 + tid];
            float x  = s + b3[0];
            float xm = fminf(x, 8.0f);
            float e  = __builtin_amdgcn_exp2f(xm * LOG2E);
            float sp = __builtin_amdgcn_logf(1.0f + e) * LN2;
            out[row0 + tid] = (x > 8.0f) ? x : sp;
        }
    }
}

extern "C" void kernel_launch(void* const* d_in, const int* in_sizes, int n_in,
                              void* d_out, int out_size, void* d_ws, size_t ws_size,
                              hipStream_t stream) {
    const float* pos = (const float*)d_in[0];
    const float* W0  = (const float*)d_in[1];
    const float* b0  = (const float*)d_in[2];
    const float* W1  = (const float*)d_in[3];
    const float* b1  = (const float*)d_in[4];
    const float* W2  = (const float*)d_in[5];
    const float* b2  = (const float*)d_in[6];
    const float* W3  = (const float*)d_in[7];
    const float* b3  = (const float*)d_in[8];
    const float* s0  = (const float*)d_in[9];
    const float* s1  = (const float*)d_in[10];
    const float* s2  = (const float*)d_in[11];

    unsigned short* wp = (unsigned short*)d_ws;              // 143360 bf16
    float* negc = (float*)((char*)d_ws + 286720);            // 2304 fp32: 3 x [np|c1|c2]

    pack_kernel<<<560, 256, 0, stream>>>(W0, W1, W2, W3, s0, s1, s2, b0, b1, b2, wp, negc);

    int nrows = in_sizes[0] / 3;          // 1048576
    int nblk  = nrows / ROWS;             // 16384
    mlp_kernel<<<nblk, 256, 0, stream>>>(pos, b3, wp, negc,
                                         (float*)d_out);
}

// Round 5
// 376.368 us; speedup vs baseline: 1.0933x; 1.0636x over previous
//
#include <hip/hip_runtime.h>
#include <hip/hip_bf16.h>
#include <math.h>

typedef __attribute__((ext_vector_type(8))) short short8;
typedef __attribute__((ext_vector_type(4))) float f32x4;
typedef __attribute__((ext_vector_type(2))) float f32x2;
typedef __attribute__((ext_vector_type(2))) unsigned int uint2v;

#define LOG2E 1.4426950408889634f
#define LN2   0.6931471805599453f

__device__ __forceinline__ unsigned short f2bf(float f) {
    union { float f; unsigned u; } v; v.f = f;
    unsigned u = v.u;
    u += 0x7fffu + ((u >> 16) & 1u);   // RNE, finite
    return (unsigned short)(u >> 16);
}
__device__ __forceinline__ float bf2f(unsigned short h) {
    union { unsigned u; float f; } v; v.u = ((unsigned)h) << 16;
    return v.f;
}
__device__ __forceinline__ unsigned pk_bf16(float a, float b) {
    __hip_bfloat162 t = __float22bfloat162_rn(float2{a, b});   // v_cvt_pk_bf16_f32
    union { __hip_bfloat162 b; unsigned u; } v; v.b = t;
    return v.u;
}
// packed FP32 ops (VOP3P, CDNA2+)
__device__ __forceinline__ f32x2 pk_add2(f32x2 a, f32x2 b) {
    f32x2 d;
    asm("v_pk_add_f32 %0, %1, %2" : "=v"(d) : "v"(a), "v"(b));
    return d;
}
__device__ __forceinline__ f32x2 pk_mul2(f32x2 a, f32x2 b) {
    f32x2 d;
    asm("v_pk_mul_f32 %0, %1, %2" : "=v"(d) : "v"(a), "v"(b));
    return d;
}

// ---------------------------------------------------------------------------
// Wave tile = 64 rows x 64 cols. Wave w owns phys cols [w*64, w*64+64).
// Tile->column map: col tile ct (0..3), frag col i: phys n = w*64 + 4*i + ct
// (4 adjacent phys cols per lane -> b64 activation writes).
// Pack order per layer: frag-set index ((w*NKS + ks)*4 + ct) -> a wave's
// layer slice is one contiguous 32 KB stream.
//   wp[(((w*NKS+ks)*4+ct)*64 + lane)*8 + j] = s_n * W[k][n],
//   k = ks*32 + (lane>>4)*8 + j,  n = w*64 + 4*(lane&15) + ct.
// SCALE FOLD: s_n = sqrt(log2e / (2 sigma_n^2)) is folded into the packed
// weights; t_n = s_n * b_n. Gaussian = exp2(-(u + t)^2) where u = MFMA out.
// Activation per element pair: pk_add + pk_mul + exp2(neg mod, free).
// (Error-equivalent to the unfolded form: dw = 2 s^2 (x+b) dx either way.)
// W0: hi/lo split rows [wh,wl,wh] per input dim of the SCALED value
// (K=9 pad 32, NKS=1).
// W3: hi/lo split into 2 B-columns (n=0: wh, n=1: wl), per-wave K-slice 64
//   at wp+139264 (unscaled).
// negc[l*256 + n] = t_n for layer l.
// R4 BUG FIX: W1/W2 branch must store wp[tid] (R4 stored wp[8192+e] after
// e -= 65536 for W2 -> W2 slice never written, W1 slice raced).
// Register budget: acc 64 AGPR + <=64 VGPR must stay <=128 total
// (R2 measured: 68+64=132 -> 3 waves/SIMD, -25% occupancy, +18us).
// __launch_bounds__(256,4) pins the allocator to that budget.
// ---------------------------------------------------------------------------
__global__ void pack_kernel(const float* __restrict__ W0, const float* __restrict__ W1,
                            const float* __restrict__ W2, const float* __restrict__ W3,
                            const float* __restrict__ s0, const float* __restrict__ s1,
                            const float* __restrict__ s2,
                            const float* __restrict__ b0, const float* __restrict__ b1,
                            const float* __restrict__ b2,
                            unsigned short* __restrict__ wp, float* __restrict__ negc) {
    int tid = blockIdx.x * 256 + threadIdx.x;    // 0 .. 143359
    if (tid < 8192) {                            // W0 (NKS=1), scaled hi/lo
        int j = tid & 7, lane = (tid >> 3) & 63, ct = (tid >> 9) & 3, w = tid >> 11;
        int k = ((lane >> 4) * 8) + j;           // 0..31
        int n = w * 64 + 4 * (lane & 15) + ct;
        unsigned short v = 0;
        if (k < 9) {
            int d = k / 3, m = k - d * 3;        // m: 0->wh 1->wl 2->wh
            float sv = s0[n];
            float sc = sqrtf(LOG2E / (2.0f * sv * sv));
            float wv = W0[d * 256 + n] * sc;
            unsigned short wh = f2bf(wv);
            v = (m == 1) ? f2bf(wv - bf2f(wh)) : wh;
        }
        wp[tid] = v;
    } else if (tid < 139264) {                   // W1 / W2 (NKS=8), scaled
        int e = tid - 8192;
        const float* W = W1;
        const float* S = s1;
        if (e >= 65536) { W = W2; S = s2; e -= 65536; }
        int j = e & 7, lane = (e >> 3) & 63, ct = (e >> 9) & 3, ks = (e >> 11) & 7, w = e >> 14;
        int k = ks * 32 + ((lane >> 4) * 8) + j;
        int n = w * 64 + 4 * (lane & 15) + ct;
        float sv = S[n];
        float sc = sqrtf(LOG2E / (2.0f * sv * sv));
        wp[tid] = f2bf(W[k * 256 + n] * sc);     // FIX: full-offset store
    } else if (tid < 143360) {                   // W3 hi/lo (2 B-cols), unscaled
        int e = tid - 139264;
        int j = e & 7, lane = (e >> 3) & 63, ks = (e >> 9) & 1, w = e >> 10;
        int i16p = lane & 15, qp = lane >> 4;
        int k = w * 64 + ks * 32 + qp * 8 + j;
        float wv = W3[k];
        unsigned short wh = f2bf(wv);
        unsigned short v = 0;
        if (i16p == 0) v = wh;
        else if (i16p == 1) v = f2bf(wv - bf2f(wh));
        wp[139264 + e] = v;
    }
    if (tid < 768) {
        int l = tid >> 8, n = tid & 255;
        const float* s = (l == 0) ? s0 : (l == 1 ? s1 : s2);
        const float* b = (l == 0) ? b0 : (l == 1 ? b1 : b2);
        float sv = s[n], bv = b[n];
        float sc = sqrtf(LOG2E / (2.0f * sv * sv));
        negc[l * 256 + n] = sc * bv;             // t_n
    }
}

constexpr int ROWS = 64;     // rows per block (256 threads = 4 waves)
constexpr int HSTR = 264;    // h row stride, bf16 elems (+8 pad; 528 B)
constexpr int ASTR = 40;     // A0 row stride (80 B)

// One MFMA layer. Each wave: all 64 rows x its 64 cols. Per ks: 4 A-frags
// (rg) + 4 W-frags (ct, contiguous stream) -> 16 MFMAs (each load feeds 4).
// acc[rg][ct]; activations packed to regs BEFORE the presync barrier.
// Activation: pk_add + pk_mul + exp2(-w) per element pair (scale folded
// into W, bias*scale = t).
template <int NKS, int SSTR>
__device__ __forceinline__ void layer(const unsigned short* __restrict__ src,
                                      const unsigned short* __restrict__ wpk,
                                      const float* __restrict__ ncp,
                                      unsigned short* __restrict__ hdst,
                                      int w, int i16, int q, bool presync) {
    f32x4 acc[4][4];
#pragma unroll
    for (int rg = 0; rg < 4; ++rg)
#pragma unroll
        for (int ct = 0; ct < 4; ++ct)
            acc[rg][ct] = f32x4{0.f, 0.f, 0.f, 0.f};

    const int lane = q * 16 + i16;
    const short8* wp8 = (const short8*)wpk + (w * NKS * 4) * 64 + lane;
    const unsigned short* abase = src + i16 * SSTR + q * 8;

#pragma unroll
    for (int ks = 0; ks < NKS; ++ks) {
        short8 a[4];
#pragma unroll
        for (int rg = 0; rg < 4; ++rg)
            a[rg] = *(const short8*)(abase + rg * 16 * SSTR + ks * 32);
#pragma unroll
        for (int ct = 0; ct < 4; ++ct) {
            short8 wf = wp8[(ks * 4 + ct) * 64];
#pragma unroll
            for (int rg = 0; rg < 4; ++rg)
                acc[rg][ct] = __builtin_amdgcn_mfma_f32_16x16x32_bf16(a[rg], wf, acc[rg][ct], 0, 0, 0);
        }
    }

    // ---- activation math BEFORE barrier ----
    const int ce = w * 64 + 4 * i16;
    const f32x4 T = *(const f32x4*)(ncp + ce);
    f32x2 tb[4];
#pragma unroll
    for (int ct = 0; ct < 4; ++ct) tb[ct] = f32x2{T[ct], T[ct]};
    uint2v av[4][4];
#pragma unroll
    for (int rg = 0; rg < 4; ++rg) {
        float gg[4][4];   // [rr][ct]
#pragma unroll
        for (int ct = 0; ct < 4; ++ct) {
            f32x2 xlo = f32x2{acc[rg][ct][0], acc[rg][ct][1]};
            f32x2 xhi = f32x2{acc[rg][ct][2], acc[rg][ct][3]};
            f32x2 ylo = pk_add2(xlo, tb[ct]);
            f32x2 yhi = pk_add2(xhi, tb[ct]);
            f32x2 wlo = pk_mul2(ylo, ylo);
            f32x2 whi = pk_mul2(yhi, yhi);
            gg[0][ct] = __builtin_amdgcn_exp2f(-wlo[0]);
            gg[1][ct] = __builtin_amdgcn_exp2f(-wlo[1]);
            gg[2][ct] = __builtin_amdgcn_exp2f(-whi[0]);
            gg[3][ct] = __builtin_amdgcn_exp2f(-whi[1]);
        }
#pragma unroll
        for (int rr = 0; rr < 4; ++rr) {
            uint2v v;
            v[0] = pk_bf16(gg[rr][0], gg[rr][1]);
            v[1] = pk_bf16(gg[rr][2], gg[rr][3]);
            av[rg][rr] = v;
        }
    }
    if (presync) __syncthreads();   // all reads of hdst done before overwrite
#pragma unroll
    for (int rg = 0; rg < 4; ++rg) {
        int rbase = rg * 16 + q * 4;
#pragma unroll
        for (int rr = 0; rr < 4; ++rr)
            *(uint2v*)&hdst[(rbase + rr) * HSTR + ce] = av[rg][rr];
    }
    __syncthreads();
}

__global__ __launch_bounds__(256, 4) void mlp_kernel(
    const float* __restrict__ pos,
    const float* __restrict__ b3,
    const unsigned short* __restrict__ Wp,
    const float* __restrict__ negc,
    float* __restrict__ out)
{
    __shared__ unsigned short h[ROWS * HSTR];   // 33792 B
    __shared__ unsigned short A0[ROWS * ASTR];  // 5120 B (reused as f32 scratch)

    const int tid  = threadIdx.x;
    const int lane = tid & 63;
    const int wave = tid >> 6;                  // column group (0..3)
    const int i16  = lane & 15, q = lane >> 4;
    const long row0 = (long)blockIdx.x * ROWS;

    // ---- build A0: row r = [p0h,p0h,p0l, p1h,p1h,p1l, p2h,p2h,p2l, 0...] ----
    if (tid < ROWS) {
        const float* pp = pos + (row0 + tid) * 3;
        float p0 = pp[0], p1 = pp[1], p2 = pp[2];
        short h0 = (short)f2bf(p0); short l0 = (short)f2bf(p0 - bf2f((unsigned short)h0));
        short h1 = (short)f2bf(p1); short l1 = (short)f2bf(p1 - bf2f((unsigned short)h1));
        short h2 = (short)f2bf(p2); short l2 = (short)f2bf(p2 - bf2f((unsigned short)h2));
        unsigned short* arow = A0 + tid * ASTR;
        *(short8*)(arow + 0)  = short8{h0, h0, l0, h1, h1, l1, h2, h2};
        *(short8*)(arow + 8)  = short8{l2, 0, 0, 0, 0, 0, 0, 0};
        *(short8*)(arow + 16) = short8{0, 0, 0, 0, 0, 0, 0, 0};
        *(short8*)(arow + 24) = short8{0, 0, 0, 0, 0, 0, 0, 0};
    }
    __syncthreads();

    // ---- layer 0 (MFMA K=32 hi/lo), layers 1,2 ----
    layer<1, ASTR>(A0, Wp,         negc,        h, wave, i16, q, false);
    layer<8, HSTR>(h,  Wp + 8192,  negc + 256,  h, wave, i16, q, true);
    layer<8, HSTR>(h,  Wp + 73728, negc + 512,  h, wave, i16, q, true);

    // ---- layer 3: per-wave K-slice dot via MFMA (hi/lo W3 in B-cols 0,1) ----
    {
        const short8* w3p = (const short8*)(Wp + 139264) + (wave * 2) * 64 + lane;
        const unsigned short* ab3 = h + i16 * HSTR + wave * 64 + q * 8;
        f32x4 acc3[4];
#pragma unroll
        for (int rg = 0; rg < 4; ++rg) acc3[rg] = f32x4{0.f, 0.f, 0.f, 0.f};
#pragma unroll
        for (int ks = 0; ks < 2; ++ks) {
            short8 wf = w3p[ks * 64];
#pragma unroll
            for (int rg = 0; rg < 4; ++rg) {
                short8 a = *(const short8*)(ab3 + rg * 16 * HSTR + ks * 32);
                acc3[rg] = __builtin_amdgcn_mfma_f32_16x16x32_bf16(a, wf, acc3[rg], 0, 0, 0);
            }
        }
        // acc3[rg][rr]: col = i16 (0: wh-part, 1: wl-part), row = rg*16+q*4+rr
        float* scr = (float*)A0;   // [wave*2+i16][64 rows] = 2 KB
        if (i16 < 2) {
#pragma unroll
            for (int rg = 0; rg < 4; ++rg)
                *(f32x4*)&scr[(wave * 2 + i16) * 64 + rg * 16 + q * 4] = acc3[rg];
        }
        __syncthreads();
        if (tid < 64) {
            float s = 0.f;
#pragma unroll
            for (int g = 0; g < 8; ++g) s += scr[g * 64 + tid];
            float x  = s + b3[0];
            float xm = fminf(x, 8.0f);
            float e  = __builtin_amdgcn_exp2f(xm * LOG2E);
            float sp = __builtin_amdgcn_logf(1.0f + e) * LN2;
            out[row0 + tid] = (x > 8.0f) ? x : sp;
        }
    }
}

extern "C" void kernel_launch(void* const* d_in, const int* in_sizes, int n_in,
                              void* d_out, int out_size, void* d_ws, size_t ws_size,
                              hipStream_t stream) {
    const float* pos = (const float*)d_in[0];
    const float* W0  = (const float*)d_in[1];
    const float* b0  = (const float*)d_in[2];
    const float* W1  = (const float*)d_in[3];
    const float* b1  = (const float*)d_in[4];
    const float* W2  = (const float*)d_in[5];
    const float* b2  = (const float*)d_in[6];
    const float* W3  = (const float*)d_in[7];
    const float* b3  = (const float*)d_in[8];
    const float* s0  = (const float*)d_in[9];
    const float* s1  = (const float*)d_in[10];
    const float* s2  = (const float*)d_in[11];

    unsigned short* wp = (unsigned short*)d_ws;              // 143360 bf16
    float* negc = (float*)((char*)d_ws + 286720);            // 768 fp32: 3 x t[256]

    pack_kernel<<<560, 256, 0, stream>>>(W0, W1, W2, W3, s0, s1, s2, b0, b1, b2, wp, negc);

    int nrows = in_sizes[0] / 3;          // 1048576
    int nblk  = nrows / ROWS;             // 16384
    mlp_kernel<<<nblk, 256, 0, stream>>>(pos, b3, wp, negc,
                                         (float*)d_out);
}

// Round 6
// 366.608 us; speedup vs baseline: 1.1224x; 1.0266x over previous
//
#include <hip/hip_runtime.h>
#include <hip/hip_bf16.h>
#include <math.h>

typedef __attribute__((ext_vector_type(8))) short short8;
typedef __attribute__((ext_vector_type(4))) float f32x4;
typedef __attribute__((ext_vector_type(2))) float f32x2;
typedef __attribute__((ext_vector_type(2))) unsigned int uint2v;

#define LOG2E 1.4426950408889634f
#define LN2   0.6931471805599453f

__device__ __forceinline__ unsigned short f2bf(float f) {
    union { float f; unsigned u; } v; v.f = f;
    unsigned u = v.u;
    u += 0x7fffu + ((u >> 16) & 1u);   // RNE, finite
    return (unsigned short)(u >> 16);
}
__device__ __forceinline__ float bf2f(unsigned short h) {
    union { unsigned u; float f; } v; v.u = ((unsigned)h) << 16;
    return v.f;
}
__device__ __forceinline__ unsigned pk_bf16(float a, float b) {
    __hip_bfloat162 t = __float22bfloat162_rn(float2{a, b});   // v_cvt_pk_bf16_f32
    union { __hip_bfloat162 b; unsigned u; } v; v.b = t;
    return v.u;
}
// packed FP32 ops (VOP3P, CDNA2+)
__device__ __forceinline__ f32x2 pk_add2(f32x2 a, f32x2 b) {
    f32x2 d;
    asm("v_pk_add_f32 %0, %1, %2" : "=v"(d) : "v"(a), "v"(b));
    return d;
}
__device__ __forceinline__ f32x2 pk_mul2(f32x2 a, f32x2 b) {
    f32x2 d;
    asm("v_pk_mul_f32 %0, %1, %2" : "=v"(d) : "v"(a), "v"(b));
    return d;
}

// ---------------------------------------------------------------------------
// Wave tile = 64 rows x 64 cols. Wave w owns phys cols [w*64, w*64+64).
// Tile->column map: col tile ct (0..3), frag col i: phys n = w*64 + 4*i + ct
// (4 adjacent phys cols per lane -> b64 activation writes).
// Pack order per layer: frag-set index ((w*NKS + ks)*4 + ct) -> a wave's
// layer slice is one contiguous 32 KB stream.
//   wp[(((w*NKS+ks)*4+ct)*64 + lane)*8 + j] = s_n * W[k][n],
//   k = ks*32 + (lane>>4)*8 + j,  n = w*64 + 4*(lane&15) + ct.
// SCALE FOLD: s_n = sqrt(log2e / (2 sigma_n^2)) is folded into the packed
// weights; t_n = s_n * b_n. Gaussian = exp2(-(u + t)^2) where u = MFMA out.
// Activation per element pair: pk_add + pk_mul + exp2(neg mod, free).
// W0: hi/lo split rows [wh,wl,wh] per input dim of the SCALED value
// (K=9 pad 32, NKS=1).
// W3: hi/lo split into 2 B-columns (n=0: wh, n=1: wl), per-wave K-slice 64
//   at wp+139264 (unscaled).
// negc[l*256 + n] = t_n for layer l.
// T5: s_setprio(1) around MFMA clusters. Resident waves come from 4
// independent blocks per SIMD at different phases -> priority boost for
// MFMA-phase waves breaks phase convoys (m191 regime; zero reg cost).
// Register budget: acc 64 AGPR + <=64 VGPR must stay <=128 total
// (R2 measured: 68+64=132 -> 3 waves/SIMD, -25% occupancy, +18us).
// __launch_bounds__(256,4) pins the allocator to that budget.
// ---------------------------------------------------------------------------
__global__ void pack_kernel(const float* __restrict__ W0, const float* __restrict__ W1,
                            const float* __restrict__ W2, const float* __restrict__ W3,
                            const float* __restrict__ s0, const float* __restrict__ s1,
                            const float* __restrict__ s2,
                            const float* __restrict__ b0, const float* __restrict__ b1,
                            const float* __restrict__ b2,
                            unsigned short* __restrict__ wp, float* __restrict__ negc) {
    int tid = blockIdx.x * 256 + threadIdx.x;    // 0 .. 143359
    if (tid < 8192) {                            // W0 (NKS=1), scaled hi/lo
        int j = tid & 7, lane = (tid >> 3) & 63, ct = (tid >> 9) & 3, w = tid >> 11;
        int k = ((lane >> 4) * 8) + j;           // 0..31
        int n = w * 64 + 4 * (lane & 15) + ct;
        unsigned short v = 0;
        if (k < 9) {
            int d = k / 3, m = k - d * 3;        // m: 0->wh 1->wl 2->wh
            float sv = s0[n];
            float sc = sqrtf(LOG2E / (2.0f * sv * sv));
            float wv = W0[d * 256 + n] * sc;
            unsigned short wh = f2bf(wv);
            v = (m == 1) ? f2bf(wv - bf2f(wh)) : wh;
        }
        wp[tid] = v;
    } else if (tid < 139264) {                   // W1 / W2 (NKS=8), scaled
        int e = tid - 8192;
        const float* W = W1;
        const float* S = s1;
        if (e >= 65536) { W = W2; S = s2; e -= 65536; }
        int j = e & 7, lane = (e >> 3) & 63, ct = (e >> 9) & 3, ks = (e >> 11) & 7, w = e >> 14;
        int k = ks * 32 + ((lane >> 4) * 8) + j;
        int n = w * 64 + 4 * (lane & 15) + ct;
        float sv = S[n];
        float sc = sqrtf(LOG2E / (2.0f * sv * sv));
        wp[tid] = f2bf(W[k * 256 + n] * sc);     // full-offset store
    } else if (tid < 143360) {                   // W3 hi/lo (2 B-cols), unscaled
        int e = tid - 139264;
        int j = e & 7, lane = (e >> 3) & 63, ks = (e >> 9) & 1, w = e >> 10;
        int i16p = lane & 15, qp = lane >> 4;
        int k = w * 64 + ks * 32 + qp * 8 + j;
        float wv = W3[k];
        unsigned short wh = f2bf(wv);
        unsigned short v = 0;
        if (i16p == 0) v = wh;
        else if (i16p == 1) v = f2bf(wv - bf2f(wh));
        wp[139264 + e] = v;
    }
    if (tid < 768) {
        int l = tid >> 8, n = tid & 255;
        const float* s = (l == 0) ? s0 : (l == 1 ? s1 : s2);
        const float* b = (l == 0) ? b0 : (l == 1 ? b1 : b2);
        float sv = s[n], bv = b[n];
        float sc = sqrtf(LOG2E / (2.0f * sv * sv));
        negc[l * 256 + n] = sc * bv;             // t_n
    }
}

constexpr int ROWS = 64;     // rows per block (256 threads = 4 waves)
constexpr int HSTR = 264;    // h row stride, bf16 elems (+8 pad; 528 B)
constexpr int ASTR = 40;     // A0 row stride (80 B)

// One MFMA layer. Each wave: all 64 rows x its 64 cols. Per ks: 4 A-frags
// (rg) + 4 W-frags (ct, contiguous stream) -> 16 MFMAs (each load feeds 4).
// acc[rg][ct]; activations packed to regs BEFORE the presync barrier.
// Activation: pk_add + pk_mul + exp2(-w) per element pair (scale folded
// into W, bias*scale = t).
template <int NKS, int SSTR>
__device__ __forceinline__ void layer(const unsigned short* __restrict__ src,
                                      const unsigned short* __restrict__ wpk,
                                      const float* __restrict__ ncp,
                                      unsigned short* __restrict__ hdst,
                                      int w, int i16, int q, bool presync) {
    f32x4 acc[4][4];
#pragma unroll
    for (int rg = 0; rg < 4; ++rg)
#pragma unroll
        for (int ct = 0; ct < 4; ++ct)
            acc[rg][ct] = f32x4{0.f, 0.f, 0.f, 0.f};

    const int lane = q * 16 + i16;
    const short8* wp8 = (const short8*)wpk + (w * NKS * 4) * 64 + lane;
    const unsigned short* abase = src + i16 * SSTR + q * 8;

    __builtin_amdgcn_s_setprio(1);   // T5: favor MFMA-phase wave on the SIMD
#pragma unroll
    for (int ks = 0; ks < NKS; ++ks) {
        short8 a[4];
#pragma unroll
        for (int rg = 0; rg < 4; ++rg)
            a[rg] = *(const short8*)(abase + rg * 16 * SSTR + ks * 32);
#pragma unroll
        for (int ct = 0; ct < 4; ++ct) {
            short8 wf = wp8[(ks * 4 + ct) * 64];
#pragma unroll
            for (int rg = 0; rg < 4; ++rg)
                acc[rg][ct] = __builtin_amdgcn_mfma_f32_16x16x32_bf16(a[rg], wf, acc[rg][ct], 0, 0, 0);
        }
    }
    __builtin_amdgcn_s_setprio(0);   // activation phase yields priority

    // ---- activation math BEFORE barrier ----
    const int ce = w * 64 + 4 * i16;
    const f32x4 T = *(const f32x4*)(ncp + ce);
    f32x2 tb[4];
#pragma unroll
    for (int ct = 0; ct < 4; ++ct) tb[ct] = f32x2{T[ct], T[ct]};
    uint2v av[4][4];
#pragma unroll
    for (int rg = 0; rg < 4; ++rg) {
        float gg[4][4];   // [rr][ct]
#pragma unroll
        for (int ct = 0; ct < 4; ++ct) {
            f32x2 xlo = f32x2{acc[rg][ct][0], acc[rg][ct][1]};
            f32x2 xhi = f32x2{acc[rg][ct][2], acc[rg][ct][3]};
            f32x2 ylo = pk_add2(xlo, tb[ct]);
            f32x2 yhi = pk_add2(xhi, tb[ct]);
            f32x2 wlo = pk_mul2(ylo, ylo);
            f32x2 whi = pk_mul2(yhi, yhi);
            gg[0][ct] = __builtin_amdgcn_exp2f(-wlo[0]);
            gg[1][ct] = __builtin_amdgcn_exp2f(-wlo[1]);
            gg[2][ct] = __builtin_amdgcn_exp2f(-whi[0]);
            gg[3][ct] = __builtin_amdgcn_exp2f(-whi[1]);
        }
#pragma unroll
        for (int rr = 0; rr < 4; ++rr) {
            uint2v v;
            v[0] = pk_bf16(gg[rr][0], gg[rr][1]);
            v[1] = pk_bf16(gg[rr][2], gg[rr][3]);
            av[rg][rr] = v;
        }
    }
    if (presync) __syncthreads();   // all reads of hdst done before overwrite
#pragma unroll
    for (int rg = 0; rg < 4; ++rg) {
        int rbase = rg * 16 + q * 4;
#pragma unroll
        for (int rr = 0; rr < 4; ++rr)
            *(uint2v*)&hdst[(rbase + rr) * HSTR + ce] = av[rg][rr];
    }
    __syncthreads();
}

__global__ __launch_bounds__(256, 4) void mlp_kernel(
    const float* __restrict__ pos,
    const float* __restrict__ b3,
    const unsigned short* __restrict__ Wp,
    const float* __restrict__ negc,
    float* __restrict__ out)
{
    __shared__ unsigned short h[ROWS * HSTR];   // 33792 B
    __shared__ unsigned short A0[ROWS * ASTR];  // 5120 B (reused as f32 scratch)

    const int tid  = threadIdx.x;
    const int lane = tid & 63;
    const int wave = tid >> 6;                  // column group (0..3)
    const int i16  = lane & 15, q = lane >> 4;
    const long row0 = (long)blockIdx.x * ROWS;

    // ---- build A0: row r = [p0h,p0h,p0l, p1h,p1h,p1l, p2h,p2h,p2l, 0...] ----
    if (tid < ROWS) {
        const float* pp = pos + (row0 + tid) * 3;
        float p0 = pp[0], p1 = pp[1], p2 = pp[2];
        short h0 = (short)f2bf(p0); short l0 = (short)f2bf(p0 - bf2f((unsigned short)h0));
        short h1 = (short)f2bf(p1); short l1 = (short)f2bf(p1 - bf2f((unsigned short)h1));
        short h2 = (short)f2bf(p2); short l2 = (short)f2bf(p2 - bf2f((unsigned short)h2));
        unsigned short* arow = A0 + tid * ASTR;
        *(short8*)(arow + 0)  = short8{h0, h0, l0, h1, h1, l1, h2, h2};
        *(short8*)(arow + 8)  = short8{l2, 0, 0, 0, 0, 0, 0, 0};
        *(short8*)(arow + 16) = short8{0, 0, 0, 0, 0, 0, 0, 0};
        *(short8*)(arow + 24) = short8{0, 0, 0, 0, 0, 0, 0, 0};
    }
    __syncthreads();

    // ---- layer 0 (MFMA K=32 hi/lo), layers 1,2 ----
    layer<1, ASTR>(A0, Wp,         negc,        h, wave, i16, q, false);
    layer<8, HSTR>(h,  Wp + 8192,  negc + 256,  h, wave, i16, q, true);
    layer<8, HSTR>(h,  Wp + 73728, negc + 512,  h, wave, i16, q, true);

    // ---- layer 3: per-wave K-slice dot via MFMA (hi/lo W3 in B-cols 0,1) ----
    {
        const short8* w3p = (const short8*)(Wp + 139264) + (wave * 2) * 64 + lane;
        const unsigned short* ab3 = h + i16 * HSTR + wave * 64 + q * 8;
        f32x4 acc3[4];
#pragma unroll
        for (int rg = 0; rg < 4; ++rg) acc3[rg] = f32x4{0.f, 0.f, 0.f, 0.f};
        __builtin_amdgcn_s_setprio(1);
#pragma unroll
        for (int ks = 0; ks < 2; ++ks) {
            short8 wf = w3p[ks * 64];
#pragma unroll
            for (int rg = 0; rg < 4; ++rg) {
                short8 a = *(const short8*)(ab3 + rg * 16 * HSTR + ks * 32);
                acc3[rg] = __builtin_amdgcn_mfma_f32_16x16x32_bf16(a, wf, acc3[rg], 0, 0, 0);
            }
        }
        __builtin_amdgcn_s_setprio(0);
        // acc3[rg][rr]: col = i16 (0: wh-part, 1: wl-part), row = rg*16+q*4+rr
        float* scr = (float*)A0;   // [wave*2+i16][64 rows] = 2 KB
        if (i16 < 2) {
#pragma unroll
            for (int rg = 0; rg < 4; ++rg)
                *(f32x4*)&scr[(wave * 2 + i16) * 64 + rg * 16 + q * 4] = acc3[rg];
        }
        __syncthreads();
        if (tid < 64) {
            float s = 0.f;
#pragma unroll
            for (int g = 0; g < 8; ++g) s += scr[g * 64 + tid];
            float x  = s + b3[0];
            float xm = fminf(x, 8.0f);
            float e  = __builtin_amdgcn_exp2f(xm * LOG2E);
            float sp = __builtin_amdgcn_logf(1.0f + e) * LN2;
            out[row0 + tid] = (x > 8.0f) ? x : sp;
        }
    }
}

extern "C" void kernel_launch(void* const* d_in, const int* in_sizes, int n_in,
                              void* d_out, int out_size, void* d_ws, size_t ws_size,
                              hipStream_t stream) {
    const float* pos = (const float*)d_in[0];
    const float* W0  = (const float*)d_in[1];
    const float* b0  = (const float*)d_in[2];
    const float* W1  = (const float*)d_in[3];
    const float* b1  = (const float*)d_in[4];
    const float* W2  = (const float*)d_in[5];
    const float* b2  = (const float*)d_in[6];
    const float* W3  = (const float*)d_in[7];
    const float* b3  = (const float*)d_in[8];
    const float* s0  = (const float*)d_in[9];
    const float* s1  = (const float*)d_in[10];
    const float* s2  = (const float*)d_in[11];

    unsigned short* wp = (unsigned short*)d_ws;              // 143360 bf16
    float* negc = (float*)((char*)d_ws + 286720);            // 768 fp32: 3 x t[256]

    pack_kernel<<<560, 256, 0, stream>>>(W0, W1, W2, W3, s0, s1, s2, b0, b1, b2, wp, negc);

    int nrows = in_sizes[0] / 3;          // 1048576
    int nblk  = nrows / ROWS;             // 16384
    mlp_kernel<<<nblk, 256, 0, stream>>>(pos, b3, wp, negc,
                                         (float*)d_out);
}